// Round 4
// baseline (431.515 us; speedup 1.0000x reference)
//
#include <hip/hip_runtime.h>
#include <hip/hip_bf16.h>

// Problem: B=32, T=2048, D=1024 (fp32 in/out)
// out = [context (B*D), attention_weights (B*T)]  (fp32, concatenated)
#define BB 32
#define TT 2048
#define DD 1024
#define TCHUNK 32               // rows per wave
#define NC (TT / TCHUNK)        // 64 chunks per batch
#define WPB 4                   // waves per block (256 threads)
#define BLOCKS_PER_B (NC / WPB) // 16 blocks per batch
#define NBLK BLOCKS_PER_B       // partials per batch (block-level)

// Workspace layout (fp32 words):
//   scores : B*T                  @ 0
//   pm     : B*NBLK               @ WS_PM
//   pl     : B*NBLK               @ WS_PL
//   pctx   : B*NBLK*D             @ WS_PCTX
//   cnt    : B ints               @ WS_CNT
#define WS_PM   (BB * TT)
#define WS_PL   (WS_PM + BB * NBLK)
#define WS_PCTX (WS_PL + BB * NBLK)
#define WS_CNT  (WS_PCTX + BB * NBLK * DD)

__global__ __launch_bounds__(256) void attn_fused(
    const float* __restrict__ query,
    const float* __restrict__ values,
    float* __restrict__ ws,
    float* __restrict__ out) {
    float* scores = ws;
    float* pm   = ws + WS_PM;
    float* pl   = ws + WS_PL;
    float* pctx = ws + WS_PCTX;
    int*   cnt  = (int*)(ws + WS_CNT);

    const int tid  = threadIdx.x;
    const int lane = tid & 63;
    const int wave = tid >> 6;
    const int b     = blockIdx.x / BLOCKS_PER_B;
    const int blkin = blockIdx.x % BLOCKS_PER_B;
    const int chunk = blkin * WPB + wave;
    const int t0    = chunk * TCHUNK;

    // Query fragment: lane covers d in {g*256 + 4*lane + j : g=0..3, j=0..3}
    const float4* qrow = (const float4*)(query + (size_t)b * DD);
    float qf[16];
#pragma unroll
    for (int g = 0; g < 4; g++) {
        float4 q4 = qrow[g * 64 + lane];
        qf[4 * g + 0] = q4.x; qf[4 * g + 1] = q4.y;
        qf[4 * g + 2] = q4.z; qf[4 * g + 3] = q4.w;
    }

    const float4* vbase = (const float4*)(values + ((size_t)b * TT + t0) * DD);

    float m = -INFINITY, l = 0.f;
    float ctx[16];
#pragma unroll
    for (int k = 0; k < 16; k++) ctx[k] = 0.f;

    // two rows in flight
    float4 cur0[4], cur1[4];
#pragma unroll
    for (int g = 0; g < 4; g++) {
        cur0[g] = vbase[g * 64 + lane];
        cur1[g] = vbase[256 + g * 64 + lane];
    }

    for (int r = 0; r < TCHUNK; r += 2) {
        float4 nxt0[4], nxt1[4];
        const bool have_next = (r + 2 < TCHUNK);
        if (have_next) {
#pragma unroll
            for (int g = 0; g < 4; g++) {
                nxt0[g] = vbase[(size_t)(r + 2) * 256 + g * 64 + lane];
                nxt1[g] = vbase[(size_t)(r + 3) * 256 + g * 64 + lane];
            }
        }
        float vf0[16], vf1[16];
#pragma unroll
        for (int g = 0; g < 4; g++) {
            vf0[4 * g + 0] = cur0[g].x; vf0[4 * g + 1] = cur0[g].y;
            vf0[4 * g + 2] = cur0[g].z; vf0[4 * g + 3] = cur0[g].w;
            vf1[4 * g + 0] = cur1[g].x; vf1[4 * g + 1] = cur1[g].y;
            vf1[4 * g + 2] = cur1[g].z; vf1[4 * g + 3] = cur1[g].w;
        }

        float s0 = 0.f, s1 = 0.f;
#pragma unroll
        for (int k = 0; k < 16; k++) {
            s0 = fmaf(qf[k], vf0[k], s0);
            s1 = fmaf(qf[k], vf1[k], s1);
        }
#pragma unroll
        for (int off = 32; off >= 1; off >>= 1) {
            s0 += __shfl_xor(s0, off, 64);
            s1 += __shfl_xor(s1, off, 64);
        }

        // online softmax updates (wave-uniform branches)
        if (s0 <= m) {
            float p = __expf(s0 - m);
            l += p;
#pragma unroll
            for (int k = 0; k < 16; k++) ctx[k] = fmaf(p, vf0[k], ctx[k]);
        } else {
            float corr = __expf(m - s0);   // exp(-inf)=0 on first row
            m = s0;
            l = fmaf(l, corr, 1.f);
#pragma unroll
            for (int k = 0; k < 16; k++) ctx[k] = fmaf(ctx[k], corr, vf0[k]);
        }
        if (s1 <= m) {
            float p = __expf(s1 - m);
            l += p;
#pragma unroll
            for (int k = 0; k < 16; k++) ctx[k] = fmaf(p, vf1[k], ctx[k]);
        } else {
            float corr = __expf(m - s1);
            m = s1;
            l = fmaf(l, corr, 1.f);
#pragma unroll
            for (int k = 0; k < 16; k++) ctx[k] = fmaf(ctx[k], corr, vf1[k]);
        }

        if (lane == 0) {
            float2* sp = (float2*)(scores + (size_t)b * TT + t0 + r);
            *sp = make_float2(s0, s1);
        }
        if (have_next) {
#pragma unroll
            for (int g = 0; g < 4; g++) { cur0[g] = nxt0[g]; cur1[g] = nxt1[g]; }
        }
    }

    // ---- block-level combine of 4 wave partials via LDS ----
    __shared__ float lds_ctx[WPB][DD];   // 16 KiB
    __shared__ float lds_m[WPB], lds_l[WPB];
    __shared__ int   s_last;

    float4* lw = (float4*)lds_ctx[wave];
#pragma unroll
    for (int g = 0; g < 4; g++)
        lw[g * 64 + lane] = make_float4(ctx[4 * g + 0], ctx[4 * g + 1],
                                        ctx[4 * g + 2], ctx[4 * g + 3]);
    if (lane == 0) { lds_m[wave] = m; lds_l[wave] = l; }
    __syncthreads();

    const float m0 = lds_m[0], m1 = lds_m[1], m2 = lds_m[2], m3 = lds_m[3];
    const float mB = fmaxf(fmaxf(m0, m1), fmaxf(m2, m3));
    const float e0 = __expf(m0 - mB), e1 = __expf(m1 - mB);
    const float e2 = __expf(m2 - mB), e3 = __expf(m3 - mB);
    const float lB = lds_l[0] * e0 + lds_l[1] * e1 + lds_l[2] * e2 + lds_l[3] * e3;

    const int bc = b * NBLK + blkin;
    {
        float4 a = ((const float4*)lds_ctx[0])[tid];
        float4 c = ((const float4*)lds_ctx[1])[tid];
        float4 d = ((const float4*)lds_ctx[2])[tid];
        float4 e = ((const float4*)lds_ctx[3])[tid];
        float4 o;
        o.x = fmaf(a.x, e0, fmaf(c.x, e1, fmaf(d.x, e2, e.x * e3)));
        o.y = fmaf(a.y, e0, fmaf(c.y, e1, fmaf(d.y, e2, e.y * e3)));
        o.z = fmaf(a.z, e0, fmaf(c.z, e1, fmaf(d.z, e2, e.z * e3)));
        o.w = fmaf(a.w, e0, fmaf(c.w, e1, fmaf(d.w, e2, e.w * e3)));
        ((float4*)(pctx + (size_t)bc * DD))[tid] = o;
    }
    if (tid == 0) { pm[bc] = mB; pl[bc] = lB; }

    // ---- last block per batch does the final reduce ----
    __threadfence();
    __syncthreads();
    if (tid == 0) s_last = (atomicAdd(&cnt[b], 1) == NBLK - 1);
    __syncthreads();
    if (!s_last) return;
    __threadfence();

    __shared__ float s_e16[NBLK];
    __shared__ float s_M, s_rL;
    if (tid < 64) {
        float mi = (tid < NBLK) ? pm[b * NBLK + tid] : -INFINITY;
        float li = (tid < NBLK) ? pl[b * NBLK + tid] : 0.f;
        float M = mi;
#pragma unroll
        for (int off = 32; off >= 1; off >>= 1) M = fmaxf(M, __shfl_xor(M, off, 64));
        float e  = __expf(mi - M);
        float lw2 = li * e;
#pragma unroll
        for (int off = 32; off >= 1; off >>= 1) lw2 += __shfl_xor(lw2, off, 64);
        if (tid < NBLK) s_e16[tid] = e;
        if (tid == 0) { s_M = M; s_rL = 1.0f / lw2; }
    }
    __syncthreads();
    const float M  = s_M;
    const float rL = s_rL;

    // context: thread tid owns float4 at d = 4*tid
    {
        const float4* base = (const float4*)(pctx + (size_t)b * NBLK * DD);
        float4 acc = make_float4(0.f, 0.f, 0.f, 0.f);
#pragma unroll
        for (int i = 0; i < NBLK; i++) {
            float4 p = base[i * (DD / 4) + tid];
            float e = s_e16[i];
            acc.x = fmaf(p.x, e, acc.x); acc.y = fmaf(p.y, e, acc.y);
            acc.z = fmaf(p.z, e, acc.z); acc.w = fmaf(p.w, e, acc.w);
        }
        acc.x *= rL; acc.y *= rL; acc.z *= rL; acc.w *= rL;
        ((float4*)(out + (size_t)b * DD))[tid] = acc;
    }

    // weights: 8 per thread
    float* wout = out + BB * DD;
#pragma unroll
    for (int k = 0; k < 8; k++) {
        int t = k * 256 + tid;
        wout[(size_t)b * TT + t] = __expf(scores[(size_t)b * TT + t] - M) * rL;
    }
}

extern "C" void kernel_launch(void* const* d_in, const int* in_sizes, int n_in,
                              void* d_out, int out_size, void* d_ws, size_t ws_size,
                              hipStream_t stream) {
    const float* query  = (const float*)d_in[0];
    const float* values = (const float*)d_in[1];
    float* ws = (float*)d_ws;
    float* out = (float*)d_out;

    // zero the per-batch arrival counters (ws is poisoned 0xAA each call)
    hipMemsetAsync(ws + WS_CNT, 0, BB * sizeof(int), stream);
    attn_fused<<<dim3(BB * BLOCKS_PER_B), dim3(256), 0, stream>>>(query, values, ws, out);
}

// Round 5
// 372.266 us; speedup vs baseline: 1.1592x; 1.1592x over previous
//
#include <hip/hip_runtime.h>
#include <hip/hip_bf16.h>

// Problem: B=32, T=2048, D=1024 (fp32 in/out)
// out = [context (B*D), attention_weights (B*T)]  (fp32, concatenated)
#define BB 32
#define TT 2048
#define DD 1024
#define TCHUNK 8                // rows per wave (small -> many blocks -> high occupancy)
#define NC (TT / TCHUNK)        // 256 chunks per batch
#define WPB 4                   // waves per block (256 threads)
#define BLOCKS_PER_B (NC / WPB) // 64 blocks per batch -> 2048 blocks total
#define NBLK BLOCKS_PER_B       // 64 block-level partials per batch

// Workspace layout (fp32 words):
//   scores : B*T            (65536)
//   pm     : B*NBLK         (2048)
//   pl     : B*NBLK         (2048)
//   pctx   : B*NBLK*D       (2097152)
#define WS_PM   (BB * TT)
#define WS_PL   (WS_PM + BB * NBLK)
#define WS_PCTX (WS_PL + BB * NBLK)

__global__ __launch_bounds__(256, 4) void attn_pass1(
    const float* __restrict__ query,
    const float* __restrict__ values,
    float* __restrict__ ws) {
    float* scores = ws;
    float* pm   = ws + WS_PM;
    float* pl   = ws + WS_PL;
    float* pctx = ws + WS_PCTX;

    const int tid  = threadIdx.x;
    const int lane = tid & 63;
    const int wave = tid >> 6;
    const int b     = blockIdx.x / BLOCKS_PER_B;
    const int blkin = blockIdx.x % BLOCKS_PER_B;
    const int chunk = blkin * WPB + wave;
    const int t0    = chunk * TCHUNK;

    // Query fragment: lane covers d in {g*256 + 4*lane + j : g=0..3, j=0..3}
    const float4* qrow = (const float4*)(query + (size_t)b * DD);
    float qf[16];
#pragma unroll
    for (int g = 0; g < 4; g++) {
        float4 q4 = qrow[g * 64 + lane];
        qf[4 * g + 0] = q4.x; qf[4 * g + 1] = q4.y;
        qf[4 * g + 2] = q4.z; qf[4 * g + 3] = q4.w;
    }

    const float4* vbase = (const float4*)(values + ((size_t)b * TT + t0) * DD);

    float m = -INFINITY, l = 0.f;
    float ctx[16];
#pragma unroll
    for (int k = 0; k < 16; k++) ctx[k] = 0.f;

    // two rows in flight
    float4 cur0[4], cur1[4];
#pragma unroll
    for (int g = 0; g < 4; g++) {
        cur0[g] = vbase[g * 64 + lane];
        cur1[g] = vbase[256 + g * 64 + lane];
    }

    for (int r = 0; r < TCHUNK; r += 2) {
        float4 nxt0[4], nxt1[4];
        const bool have_next = (r + 2 < TCHUNK);
        if (have_next) {
#pragma unroll
            for (int g = 0; g < 4; g++) {
                nxt0[g] = vbase[(size_t)(r + 2) * 256 + g * 64 + lane];
                nxt1[g] = vbase[(size_t)(r + 3) * 256 + g * 64 + lane];
            }
        }
        float vf0[16], vf1[16];
#pragma unroll
        for (int g = 0; g < 4; g++) {
            vf0[4 * g + 0] = cur0[g].x; vf0[4 * g + 1] = cur0[g].y;
            vf0[4 * g + 2] = cur0[g].z; vf0[4 * g + 3] = cur0[g].w;
            vf1[4 * g + 0] = cur1[g].x; vf1[4 * g + 1] = cur1[g].y;
            vf1[4 * g + 2] = cur1[g].z; vf1[4 * g + 3] = cur1[g].w;
        }

        float s0 = 0.f, s1 = 0.f;
#pragma unroll
        for (int k = 0; k < 16; k++) {
            s0 = fmaf(qf[k], vf0[k], s0);
            s1 = fmaf(qf[k], vf1[k], s1);
        }
#pragma unroll
        for (int off = 32; off >= 1; off >>= 1) {
            s0 += __shfl_xor(s0, off, 64);
            s1 += __shfl_xor(s1, off, 64);
        }

        // online softmax updates (wave-uniform branches)
        if (s0 <= m) {
            float p = __expf(s0 - m);
            l += p;
#pragma unroll
            for (int k = 0; k < 16; k++) ctx[k] = fmaf(p, vf0[k], ctx[k]);
        } else {
            float corr = __expf(m - s0);   // exp(-inf)=0 on first row
            m = s0;
            l = fmaf(l, corr, 1.f);
#pragma unroll
            for (int k = 0; k < 16; k++) ctx[k] = fmaf(ctx[k], corr, vf0[k]);
        }
        if (s1 <= m) {
            float p = __expf(s1 - m);
            l += p;
#pragma unroll
            for (int k = 0; k < 16; k++) ctx[k] = fmaf(p, vf1[k], ctx[k]);
        } else {
            float corr = __expf(m - s1);
            m = s1;
            l = fmaf(l, corr, 1.f);
#pragma unroll
            for (int k = 0; k < 16; k++) ctx[k] = fmaf(ctx[k], corr, vf1[k]);
        }

        if (lane == 0) {
            float2* sp = (float2*)(scores + (size_t)b * TT + t0 + r);
            *sp = make_float2(s0, s1);
        }
        if (have_next) {
#pragma unroll
            for (int g = 0; g < 4; g++) { cur0[g] = nxt0[g]; cur1[g] = nxt1[g]; }
        }
    }

    // ---- block-level combine of 4 wave partials via LDS ----
    __shared__ float lds_ctx[WPB][DD];   // 16 KiB
    __shared__ float lds_m[WPB], lds_l[WPB];

    float4* lw = (float4*)lds_ctx[wave];
#pragma unroll
    for (int g = 0; g < 4; g++)
        lw[g * 64 + lane] = make_float4(ctx[4 * g + 0], ctx[4 * g + 1],
                                        ctx[4 * g + 2], ctx[4 * g + 3]);
    if (lane == 0) { lds_m[wave] = m; lds_l[wave] = l; }
    __syncthreads();

    const float m0 = lds_m[0], m1 = lds_m[1], m2 = lds_m[2], m3 = lds_m[3];
    const float mB = fmaxf(fmaxf(m0, m1), fmaxf(m2, m3));
    const float e0 = __expf(m0 - mB), e1 = __expf(m1 - mB);
    const float e2 = __expf(m2 - mB), e3 = __expf(m3 - mB);
    const float lB = lds_l[0] * e0 + lds_l[1] * e1 + lds_l[2] * e2 + lds_l[3] * e3;

    const int bc = b * NBLK + blkin;
    {
        float4 a = ((const float4*)lds_ctx[0])[tid];
        float4 c = ((const float4*)lds_ctx[1])[tid];
        float4 d = ((const float4*)lds_ctx[2])[tid];
        float4 e = ((const float4*)lds_ctx[3])[tid];
        float4 o;
        o.x = fmaf(a.x, e0, fmaf(c.x, e1, fmaf(d.x, e2, e.x * e3)));
        o.y = fmaf(a.y, e0, fmaf(c.y, e1, fmaf(d.y, e2, e.y * e3)));
        o.z = fmaf(a.z, e0, fmaf(c.z, e1, fmaf(d.z, e2, e.z * e3)));
        o.w = fmaf(a.w, e0, fmaf(c.w, e1, fmaf(d.w, e2, e.w * e3)));
        ((float4*)(pctx + (size_t)bc * DD))[tid] = o;
    }
    if (tid == 0) { pm[bc] = mB; pl[bc] = lB; }
}

__global__ __launch_bounds__(256) void attn_pass2(
    const float* __restrict__ ws,
    float* __restrict__ out) {
    const float* scores = ws;
    const float* pm   = ws + WS_PM;
    const float* pl   = ws + WS_PL;
    const float* pctx = ws + WS_PCTX;

    const int tid   = threadIdx.x;
    const int b     = blockIdx.x >> 2;
    const int slice = blockIdx.x & 3;

    __shared__ float s_e[NBLK];
    __shared__ float s_M, s_L;
    if (tid < 64) {  // wave 0: reduce the 64 block partials
        float mi = pm[b * NBLK + tid];
        float li = pl[b * NBLK + tid];
        float M = mi;
#pragma unroll
        for (int off = 32; off >= 1; off >>= 1) M = fmaxf(M, __shfl_xor(M, off, 64));
        float e  = __expf(mi - M);
        float lw = li * e;
#pragma unroll
        for (int off = 32; off >= 1; off >>= 1) lw += __shfl_xor(lw, off, 64);
        s_e[tid] = e;
        if (tid == 0) { s_M = M; s_L = lw; }
    }
    __syncthreads();
    const float M  = s_M;
    const float rL = 1.0f / s_L;

    // context slice: d = slice*256 + tid
    const int d = slice * 256 + tid;
    const float* base = pctx + (size_t)b * NBLK * DD + d;
    float acc = 0.f;
#pragma unroll 8
    for (int i = 0; i < NBLK; i++) acc = fmaf(base[(size_t)i * DD], s_e[i], acc);
    out[(size_t)b * DD + d] = acc * rL;

    // weights: t = slice*512 + k*256 + tid
    float* wout = out + BB * DD;
#pragma unroll
    for (int k = 0; k < 2; k++) {
        int t = slice * 512 + k * 256 + tid;
        float w = __expf(scores[(size_t)b * TT + t] - M) * rL;
        wout[(size_t)b * TT + t] = w;
    }
}

extern "C" void kernel_launch(void* const* d_in, const int* in_sizes, int n_in,
                              void* d_out, int out_size, void* d_ws, size_t ws_size,
                              hipStream_t stream) {
    const float* query  = (const float*)d_in[0];
    const float* values = (const float*)d_in[1];
    float* ws = (float*)d_ws;
    float* out = (float*)d_out;

    attn_pass1<<<dim3(BB * BLOCKS_PER_B), dim3(256), 0, stream>>>(query, values, ws);
    attn_pass2<<<dim3(BB * 4), dim3(256), 0, stream>>>(ws, out);
}